// Round 8
// baseline (256.047 us; speedup 1.0000x reference)
//
#include <hip/hip_runtime.h>
#include <math.h>

// SO3 convolution lmax=2 — 4 dispatches, one edge per wave in the hot kernel.
//   0) memsetAsync cnt[A]=0
//   1) prep (E blocks x 64): Y -> M[s1][s3] in LDS (once per edge), stored to
//      Mall[e] (84-dword padded); per-atom edge list via cursor atomic.
//   2) main (A*16 blocks x 256 = 4 waves): block = (atom a, chunk q of 4
//      edges). Wave w handles edge k=4q+w — NO per-wave loop, no dependent
//      chain, no fences, no float atomics. 12000 live edge-waves give
//      ~12 waves/SIMD of latency hiding (R1-class TLP, R7-class traffic).
//      Per edge: xj 9xf2, M 21xf4 (uniform), Wf 60xf2 (L1-hot), ~230 VALU.
//      4-wave LDS reduce -> ONE slot store per chunk (plain coalesced).
//   3) reduce (A blocks x 256): sum ceil(deg/4) contiguous slots -> out
//      (writes all 1152 floats per atom: covers 0xAA poison, zeros deg=0).

#define S9     9
#define NF     128
#define NRAD   20
#define MAXDEG 64
#define NCHK   16       // MAXDEG/4 chunks per atom
#define MSTR   84       // padded dwords per edge in Mall (81 used, 21 float4)

__device__ inline float2 f2fma(float a, float2 b, float2 c) {
    return make_float2(fmaf(a, b.x, c.x), fmaf(a, b.y, c.y));
}

// ---------------- kernel 1: per-edge prep ----------------
__global__ __launch_bounds__(64) void prep_kernel(
    const float* __restrict__ dir,      // [E, 3]
    const float* __restrict__ cg_vals,  // [ncg]
    const int* __restrict__ idx_i,      // [E]
    const int* __restrict__ cg_i1,
    const int* __restrict__ cg_i2,
    const int* __restrict__ cg_i3,
    int ncg,
    int* __restrict__ cnt,              // [A]
    int* __restrict__ elist,            // [A, MAXDEG]
    float* __restrict__ Mall)           // [E, MSTR]  (transposed [s1][s3])
{
    const int e = blockIdx.x;
    const int t = threadIdx.x;

    __shared__ __align__(16) float Msh[MSTR];
    __shared__ float Ysh[9];

    Msh[t] = 0.0f;                      // t in [0,64)
    if (t < MSTR - 64) Msh[t + 64] = 0.0f;

    if (t == 0) {
        float dx = dir[3 * e], dy = dir[3 * e + 1], dz = dir[3 * e + 2];
        const float inv = rsqrtf(dx * dx + dy * dy + dz * dz);
        dx *= inv; dy *= inv; dz *= inv;
        const float s3c  = 1.7320508075688772f;   // sqrt(3)
        const float s5c  = 2.2360679774997896f;   // sqrt(5)
        const float s15c = 3.8729833462074170f;   // sqrt(15)
        Ysh[0] = 1.0f;
        Ysh[1] = s3c * dy;
        Ysh[2] = s3c * dz;
        Ysh[3] = s3c * dx;
        Ysh[4] = s15c * dx * dy;
        Ysh[5] = s15c * dy * dz;
        Ysh[6] = 0.5f * s5c * (3.0f * dz * dz - 1.0f);
        Ysh[7] = s15c * dx * dz;
        Ysh[8] = 0.5f * s15c * (dx * dx - dy * dy);
        const int i = idx_i[e];
        const int pos = atomicAdd(&cnt[i], 1);
        if (pos < MAXDEG) elist[i * MAXDEG + pos] = e;
    }
    __syncthreads();

    // sparse CG -> M (transposed: slot = s1*9 + s3, range [0,81))
    for (int k = t; k < ncg; k += 64)
        atomicAdd(&Msh[cg_i1[k] * S9 + cg_i3[k]], cg_vals[k] * Ysh[cg_i2[k]]);
    __syncthreads();

    float* mp = Mall + (size_t)e * MSTR;
    mp[t] = Msh[t];
    if (t < MSTR - 64) mp[t + 64] = Msh[t + 64];
}

// ---------------- kernel 2: one edge per wave ----------------
__global__ __launch_bounds__(256) void main_kernel(
    const float* __restrict__ x,        // [A, 9, 128]
    const float* __restrict__ radial,   // [E, 20]
    const float* __restrict__ cutoff,   // [E]
    const float* __restrict__ Wf,       // [20, 384]
    const float* __restrict__ bf,       // [384]
    const int* __restrict__ idx_j,      // [E]
    const int* __restrict__ cnt,        // [A]
    const int* __restrict__ elist,      // [A, MAXDEG]
    const float* __restrict__ Mall,     // [E, MSTR]
    float* __restrict__ slots)          // [A*NCHK, 9*128]
{
    const int a = blockIdx.x / NCHK;
    const int q = blockIdx.x - a * NCHK;
    const int deg = min(cnt[a], MAXDEG);
    if (q * 4 >= deg) return;           // block-uniform early exit (before barrier)

    const int tid = threadIdx.x;
    const int w = tid >> 6;             // wave 0..3
    const int t = tid & 63;             // f-pair: f = 2t, 2t+1
    const int k = q * 4 + w;            // this wave's edge index
    const bool live = (k < deg);        // wave-uniform

    __shared__ float2 sacc[4][S9 * 64]; // 18.4 KB

    float2 acc[S9];
    #pragma unroll
    for (int s = 0; s < S9; ++s) acc[s] = make_float2(0.f, 0.f);

    if (live) {
        const int e = __builtin_amdgcn_readfirstlane(elist[a * MAXDEG + k]);
        const int j = __builtin_amdgcn_readfirstlane(idx_j[e]);

        // longest-latency loads first: neighbor features + M block
        const float2* xp = (const float2*)(x + (size_t)j * (S9 * NF)) + t;
        float2 xj[S9];
        #pragma unroll
        for (int s = 0; s < S9; ++s) xj[s] = xp[s * 64];

        float m[MSTR];
        {
            const float4* mp4 = (const float4*)(Mall + (size_t)e * MSTR);
            #pragma unroll
            for (int p = 0; p < MSTR / 4; ++p)
                *(float4*)&m[4 * p] = mp4[p];   // uniform address -> broadcast
        }

        // radial filter: rad/cut uniform scalars, Wf rows L1-hot
        const float* rp = radial + (size_t)e * NRAD;
        const float cut = cutoff[e];
        float2 wl0 = ((const float2*)(bf + 0 * NF))[t];
        float2 wl1 = ((const float2*)(bf + 1 * NF))[t];
        float2 wl2 = ((const float2*)(bf + 2 * NF))[t];
        #pragma unroll
        for (int r = 0; r < NRAD; ++r) {
            const float rr = rp[r];
            const float2* row = (const float2*)(Wf + r * (3 * NF));
            wl0 = f2fma(rr, row[t],       wl0);
            wl1 = f2fma(rr, row[t + 64],  wl1);
            wl2 = f2fma(rr, row[t + 128], wl2);
        }
        wl0.x *= cut; wl0.y *= cut;
        wl1.x *= cut; wl1.y *= cut;
        wl2.x *= cut; wl2.y *= cut;

        // ts[s3] = sum_s1 M[s1][s3] * xj[s1]
        float2 ts[S9];
        #pragma unroll
        for (int s = 0; s < S9; ++s) ts[s] = make_float2(0.f, 0.f);
        #pragma unroll
        for (int s1 = 0; s1 < S9; ++s1) {
            #pragma unroll
            for (int s3 = 0; s3 < S9; ++s3)
                ts[s3] = f2fma(m[s1 * S9 + s3], xj[s1], ts[s3]);
        }
        #pragma unroll
        for (int s3 = 0; s3 < S9; ++s3) {
            const float2 ww = (s3 == 0) ? wl0 : ((s3 < 4) ? wl1 : wl2);
            acc[s3].x = ww.x * ts[s3].x;
            acc[s3].y = ww.y * ts[s3].y;
        }
    }

    // cross-wave reduction (dead waves contribute zeros)
    #pragma unroll
    for (int s = 0; s < S9; ++s) sacc[w][s * 64 + t] = acc[s];
    __syncthreads();

    float2* sp = (float2*)(slots + (size_t)(a * NCHK + q) * (S9 * NF));
    for (int idx = tid; idx < S9 * 64; idx += 256) {
        float2 v0 = sacc[0][idx];
        float2 v1 = sacc[1][idx];
        float2 v2 = sacc[2][idx];
        float2 v3 = sacc[3][idx];
        sp[idx] = make_float2((v0.x + v1.x) + (v2.x + v3.x),
                              (v0.y + v1.y) + (v2.y + v3.y));
    }
}

// ---------------- kernel 3: per-atom slot reduce ----------------
__global__ __launch_bounds__(256) void reduce_kernel(
    const float* __restrict__ slots,    // [A*NCHK, 9*128]
    const int* __restrict__ cnt,        // [A]
    float* __restrict__ out)            // [A, 9, 128]
{
    const int a = blockIdx.x;
    const int tid = threadIdx.x;
    const int deg = min(cnt[a], MAXDEG);
    const int nch = (deg + 3) >> 2;

    const float2* sp = (const float2*)(slots + (size_t)a * NCHK * (S9 * NF));
    float2* op = (float2*)(out + (size_t)a * (S9 * NF));

    for (int idx = tid; idx < S9 * 64; idx += 256) {
        float2 v = make_float2(0.f, 0.f);
        for (int ch = 0; ch < nch; ++ch) {
            float2 u = sp[(size_t)ch * (S9 * 64) + idx];
            v.x += u.x; v.y += u.y;
        }
        op[idx] = v;   // every element written: covers poison, zeros deg=0
    }
}

extern "C" void kernel_launch(void* const* d_in, const int* in_sizes, int n_in,
                              void* d_out, int out_size, void* d_ws, size_t ws_size,
                              hipStream_t stream) {
    const float* x       = (const float*)d_in[0];
    const float* radial  = (const float*)d_in[1];
    const float* dir     = (const float*)d_in[2];
    const float* cutoff  = (const float*)d_in[3];
    const float* Wf      = (const float*)d_in[4];
    const float* bf      = (const float*)d_in[5];
    const float* cg_vals = (const float*)d_in[6];
    const int*   idx_i   = (const int*)d_in[7];
    const int*   idx_j   = (const int*)d_in[8];
    const int*   cg_i1   = (const int*)d_in[9];
    const int*   cg_i2   = (const int*)d_in[10];
    const int*   cg_i3   = (const int*)d_in[11];
    // d_in[12] = w_idx: unused (w_idx[k] == l(cg_idx_out[k]), folded into kernel)

    const int E   = in_sizes[7];
    const int ncg = in_sizes[6];
    const int A   = in_sizes[0] / (S9 * NF);

    // ws: cnt[A] | elist[A*MAXDEG] | align | Mall[E*MSTR] | slots[A*NCHK*1152]
    int* cnt   = (int*)d_ws;
    int* elist = cnt + A;
    size_t off = ((size_t)(A + A * MAXDEG) * sizeof(int) + 511) & ~(size_t)511;
    float* Mall  = (float*)((char*)d_ws + off);
    float* slots = Mall + (size_t)E * MSTR;

    hipMemsetAsync(cnt, 0, (size_t)A * sizeof(int), stream);

    prep_kernel<<<E, 64, 0, stream>>>(
        dir, cg_vals, idx_i, cg_i1, cg_i2, cg_i3, ncg, cnt, elist, Mall);

    main_kernel<<<A * NCHK, 256, 0, stream>>>(
        x, radial, cutoff, Wf, bf, idx_j, cnt, elist, Mall, slots);

    reduce_kernel<<<A, 256, 0, stream>>>(slots, cnt, (float*)d_out);
}